// Round 7
// baseline (8441.483 us; speedup 1.0000x reference)
//
#include <hip/hip_runtime.h>
#include <hip/hip_fp16.h>

#define N_INP 256
#define NH    2048
#define NOUT  256
#define BB    64
#define TT    512
#define GRIDN 128          // k_step workgroups, 16 output cols each
#define NWAVE (GRIDN * 4)  // per-step flags: [row-group w][producer WG j]

typedef __bf16 bf16x8 __attribute__((ext_vector_type(8)));
typedef float  f32x4  __attribute__((ext_vector_type(4)));

__device__ __forceinline__ unsigned short f2bf(float f) {
  unsigned u = __float_as_uint(f);
  u += 0x7fffu + ((u >> 16) & 1u);          // RTNE
  return (unsigned short)(u >> 16);
}

__device__ __forceinline__ float fast_tanh(float x) {
  x = fminf(9.0f, fmaxf(-9.0f, x));
  float e = __expf(2.0f * x);
  return (e - 1.0f) / (e + 1.0f);
}

__device__ __forceinline__ f32x4 mfma16(uint4 a, uint4 b, f32x4 c) {
  return __builtin_amdgcn_mfma_f32_16x16x32_bf16(
      __builtin_bit_cast(bf16x8, a), __builtin_bit_cast(bf16x8, b), c, 0, 0, 0);
}

// ---------------- prep: zero barrier flags ----------------
__global__ void k_zero(unsigned* __restrict__ p, int n) {
  int i = blockIdx.x * 256 + threadIdx.x;
  if (i < n) p[i] = 0;
}

// ---------------- prep: u (B,T,256) f32 -> ut (T*B, 256) bf16 ----------------
__global__ void k_ut(const float* __restrict__ u, unsigned short* __restrict__ ut) {
  int idx = blockIdx.x * 256 + threadIdx.x;    // over 64*512*64 float4 units
  int k4 = idx & 63;
  int rowbt = idx >> 6;                        // row = t*64+b
  int t = rowbt >> 6, b = rowbt & 63;
  float4 f = *(const float4*)(u + ((size_t)b * TT + t) * N_INP + k4 * 4);
  uint2 pk;
  pk.x = f2bf(f.x) | ((unsigned)f2bf(f.y) << 16);
  pk.y = f2bf(f.z) | ((unsigned)f2bf(f.w) << 16);
  *(uint2*)(ut + (size_t)rowbt * N_INP + k4 * 4) = pk;
}

// ------------- prep: W (K,N) f32 row-major -> B-fragment-ordered bf16 --------
// Wf layout: [kb][nt][lane][8], blockIdx.x = kb*(N/16)+nt
__global__ void k_swz(const float* __restrict__ W, unsigned short* __restrict__ Wf, int N) {
  int lane = threadIdx.x;
  int nt16 = N >> 4;
  int kb = blockIdx.x / nt16;
  int nt = blockIdx.x - kb * nt16;
  int k0 = kb * 32 + ((lane >> 4) << 3);
  int c  = nt * 16 + (lane & 15);
  unsigned short v[8];
#pragma unroll
  for (int j = 0; j < 8; ++j) v[j] = f2bf(W[(size_t)(k0 + j) * N + c]);
  uint4 p;
  p.x = v[0] | ((unsigned)v[1] << 16);
  p.y = v[2] | ((unsigned)v[3] << 16);
  p.z = v[4] | ((unsigned)v[5] << 16);
  p.w = v[6] | ((unsigned)v[7] << 16);
  ((uint4*)Wf)[(size_t)blockIdx.x * 64 + lane] = p;
}

// ---------------- persistent recurrence kernel (cooperative) -----------------
// 128 WGs x 1024 threads (16 waves). Wave (w,h): row-group w (rows 16w..16w+16),
// K-quarter h (H-chunks h*16..h*16+16, input chunks 2h..2h+2). The four
// K-quarter waves of a row-group run their MALL load chains CONCURRENTLY
// (TLP latency hiding — the compiler cannot collapse wave parallelism the way
// it collapses register prefetch depth). Partial accumulators combine via LDS
// with two __syncthreads; lead wave (h=0) does epilogue + H store + flag.
// Flag/fence/store machinery byte-identical to the r4-verified kernel; sibling
// release via monotonic LDS counter (r0-verified pattern). No sched_barrier,
// no inline-asm loads.
__global__ __launch_bounds__(1024) void k_step(
    const float* __restrict__ Whh, const float* __restrict__ Wuh,
    const float* __restrict__ b_h, const float* __restrict__ tau,
    const float* __restrict__ h0, const unsigned short* __restrict__ ut,
    unsigned short* __restrict__ H, unsigned* __restrict__ flags) {
  __shared__ unsigned short lds[64 * 64 * 8];   // 64 KiB: W_hh frags [kb][lane][8]
  __shared__ f32x4 ldsP[12 * 64 * 4];           // 48 KiB: partials [(h-1)*4+w][lane][4]
  __shared__ unsigned bar_cnt[4];               // per-row-group release counter
  const int cgp = blockIdx.x;       // colgroup 0..127
  const int tid = threadIdx.x;
  const int wid = tid >> 6;         // 0..15
  const int w = wid >> 2;           // row-group 0..3
  const int h = wid & 3;            // K-quarter 0..3
  const int lane = tid & 63;
  const int q = lane >> 4, p = lane & 15;

  // one-time: stage W_hh column slice into LDS in B-fragment order
  for (int s = tid; s < 64 * 64; s += 1024) {
    int kb = s >> 6, l = s & 63;
    int k0 = kb * 32 + ((l >> 4) << 3);
    int c = cgp * 16 + (l & 15);
    unsigned short v[8];
#pragma unroll
    for (int j = 0; j < 8; ++j) v[j] = f2bf(Whh[(size_t)(k0 + j) * NH + c]);
    uint4 pk;
    pk.x = v[0] | ((unsigned)v[1] << 16);
    pk.y = v[2] | ((unsigned)v[3] << 16);
    pk.z = v[4] | ((unsigned)v[5] << 16);
    pk.w = v[6] | ((unsigned)v[7] << 16);
    ((uint4*)lds)[s] = pk;
  }
  if (tid < 4) bar_cnt[tid] = 0;

  const int c = cgp * 16 + p;                 // this lane's output column
  const float al = 1.0f / tau[c];
  const float onem = 1.0f - al;
  const float bh_c = b_h[c];
  const float h0c = fminf(1.0f, fmaxf(-1.0f, h0[c]));
  float hprev[4] = {h0c, h0c, h0c, h0c};      // used by lead wave only
  const int rbase = w * 16;                   // batch-row base of this row-group
  const bool even = (p & 1) == 0;
  const int halfc = cgp * 8 + (p >> 1);       // dword column for packed stores
  unsigned* H32 = (unsigned*)H;

  // one-time: this wave's W_uh B-fragments (input chunks 2h, 2h+1)
  uint4 wu[2];
#pragma unroll
  for (int i = 0; i < 2; ++i) {
    int kbg = 2 * h + i;
    unsigned short v[8];
#pragma unroll
    for (int j = 0; j < 8; ++j)
      v[j] = f2bf(Wuh[(size_t)(kbg * 32 + q * 8 + j) * NH + c]);
    wu[i].x = v[0] | ((unsigned)v[1] << 16);
    wu[i].y = v[2] | ((unsigned)v[3] << 16);
    wu[i].z = v[4] | ((unsigned)v[5] << 16);
    wu[i].w = v[6] | ((unsigned)v[7] << 16);
  }

  __syncthreads();   // LDS staging + bar_cnt visible

  // init H[0]: lead waves only (cover all 16 rows of their row-group)
  if (h == 0) {
    unsigned mine = f2bf(h0c);
    unsigned other = (unsigned)__shfl_xor((int)mine, 1);
    unsigned pk0 = even ? (mine | (other << 16)) : (other | (mine << 16));
    if (even) {
#pragma unroll
      for (int r = 0; r < 4; ++r)
        __hip_atomic_store(H32 + (size_t)(rbase + q * 4 + r) * (NH / 2) + halfc,
                           pk0, __ATOMIC_RELAXED, __HIP_MEMORY_SCOPE_AGENT);
    }
    __builtin_amdgcn_fence(__ATOMIC_RELEASE, "workgroup");  // drain H[0] stores
    if (lane == 0)
      __hip_atomic_store(flags + (size_t)w * GRIDN + cgp, 1u, __ATOMIC_RELAXED,
                         __HIP_MEMORY_SCOPE_AGENT);
  }

  const uint4* ldsv = (const uint4*)lds;
  const int kb0 = h * 16;                     // this wave's H-chunk base
  const int slot = ((h - 1) * 4 + w) * 256 + lane * 4;   // partial write slot (h>0)
  f32x4 acc[4];

  for (int t = 0; t < TT; ++t) {
    // input drive for step t (barrier-independent; overlaps flag propagation)
    {
      const uint4* Au = (const uint4*)(ut + ((size_t)t * BB + rbase + p) * N_INP + q * 8);
#pragma unroll
      for (int j = 0; j < 4; ++j) acc[j] = (f32x4){0.f, 0.f, 0.f, 0.f};
#pragma unroll
      for (int i = 0; i < 2; ++i) {
        int kbg = 2 * h + i;
        acc[kbg & 3] = mfma16(Au[kbg * 4], wu[i], acc[kbg & 3]);
      }
    }

    // lead wave polls this row-group's 128 producer flags; siblings spin on LDS
    if (h == 0) {
      const unsigned* fl = flags + (size_t)t * NWAVE + w * GRIDN;
      for (;;) {
        unsigned v0 = __hip_atomic_load(fl + lane, __ATOMIC_RELAXED,
                                        __HIP_MEMORY_SCOPE_AGENT);
        unsigned v1 = __hip_atomic_load(fl + 64 + lane, __ATOMIC_RELAXED,
                                        __HIP_MEMORY_SCOPE_AGENT);
        if (__all((v0 != 0u) && (v1 != 0u))) break;
      }
      __builtin_amdgcn_fence(__ATOMIC_ACQUIRE, "workgroup");
      __hip_atomic_store(&bar_cnt[w], (unsigned)(t + 1), __ATOMIC_RELAXED,
                         __HIP_MEMORY_SCOPE_WORKGROUP);
    } else {
      while (__hip_atomic_load(&bar_cnt[w], __ATOMIC_RELAXED,
                               __HIP_MEMORY_SCOPE_WORKGROUP) < (unsigned)(t + 1))
        __builtin_amdgcn_s_sleep(1);
      __builtin_amdgcn_fence(__ATOMIC_ACQUIRE, "workgroup");
    }

    // this wave's 16 H-chunks (compiler-scheduled, r4-proven pattern)
    const uint4* Ar = (const uint4*)(H + (size_t)t * BB * NH +
                                     (size_t)(rbase + p) * NH + q * 8);
    uint4 a[8], an[8];
#pragma unroll
    for (int j = 0; j < 8; ++j) a[j] = Ar[(kb0 + j) * 4];
#pragma unroll
    for (int j = 0; j < 8; ++j) an[j] = Ar[(kb0 + 8 + j) * 4];
#pragma unroll
    for (int j = 0; j < 8; ++j)
      acc[(kb0 + j) & 3] = mfma16(a[j], ldsv[(kb0 + j) * 64 + lane], acc[(kb0 + j) & 3]);
#pragma unroll
    for (int j = 0; j < 8; ++j)
      acc[(kb0 + 8 + j) & 3] =
          mfma16(an[j], ldsv[(kb0 + 8 + j) * 64 + lane], acc[(kb0 + 8 + j) & 3]);

    // combine partials across the 4 K-quarter waves of this row-group
    if (h != 0) {
#pragma unroll
      for (int ci = 0; ci < 4; ++ci) ldsP[slot + ci] = acc[ci];
    }
    __syncthreads();                 // partials visible
    f32x4 p1[4], p2[4], p3[4];
    if (h == 0) {
#pragma unroll
      for (int ci = 0; ci < 4; ++ci) {
        p1[ci] = ldsP[(0 * 4 + w) * 256 + lane * 4 + ci];
        p2[ci] = ldsP[(1 * 4 + w) * 256 + lane * 4 + ci];
        p3[ci] = ldsP[(2 * 4 + w) * 256 + lane * 4 + ci];
      }
    }
    __syncthreads();                 // lead has read; buffer reusable next step

    if (h == 0) {
#pragma unroll
      for (int ci = 0; ci < 4; ++ci)
        acc[ci] = ((acc[ci] + p1[ci]) + p2[ci]) + p3[ci];   // chunk-order h=0..3

      // epilogue: leaky update, packed write-through store of H[t+1]
      unsigned* H32n = H32 + (size_t)(t + 1) * BB * (NH / 2);
#pragma unroll
      for (int r = 0; r < 4; ++r) {
        float pre = acc[0][r] + acc[1][r] + acc[2][r] + acc[3][r] + bh_c;
        float hn = onem * hprev[r] + al * fast_tanh(pre);
        hprev[r] = hn;
        unsigned mine = f2bf(hn);
        unsigned other = (unsigned)__shfl_xor((int)mine, 1);
        unsigned pk = even ? (mine | (other << 16)) : (other | (mine << 16));
        if (even)
          __hip_atomic_store(H32n + (size_t)(rbase + q * 4 + r) * (NH / 2) + halfc,
                             pk, __ATOMIC_RELAXED, __HIP_MEMORY_SCOPE_AGENT);
      }

      __builtin_amdgcn_fence(__ATOMIC_RELEASE, "workgroup");  // drain H[t+1] stores
      if (lane == 0)
        __hip_atomic_store(flags + (size_t)(t + 1) * NWAVE + w * GRIDN + cgp, 1u,
                           __ATOMIC_RELAXED, __HIP_MEMORY_SCOPE_AGENT);
    }
  }
}

// ---------------- phase 2: Y = softmax(H[1..T] @ W_hy + b_y) -----------------
// 512 WGs x 256 thr; WG = 64 rows (wave = 16), N = 256 (16 n-tiles)
__global__ __launch_bounds__(256) void k_y(
    const unsigned short* __restrict__ H, const unsigned short* __restrict__ Wyf,
    const float* __restrict__ b_y, float* __restrict__ out) {
  int wave = threadIdx.x >> 6, lane = threadIdx.x & 63;
  int q = lane >> 4, p = lane & 15;
  int R = blockIdx.x * 64 + wave * 16;          // row = t*64+b
  const uint4* A = (const uint4*)(H + (size_t)(R + BB + p) * NH + q * 8);  // +BB: skip H[0]
  const uint4* Bf = (const uint4*)Wyf;
  f32x4 acc[16];
#pragma unroll
  for (int nt = 0; nt < 16; ++nt) acc[nt] = (f32x4){0.f, 0.f, 0.f, 0.f};
  for (int kb = 0; kb < 64; ++kb) {
    uint4 a = A[kb * 4];
#pragma unroll
    for (int nt = 0; nt < 16; ++nt) {
      uint4 b = Bf[(size_t)(kb * 16 + nt) * 64 + lane];
      acc[nt] = mfma16(a, b, acc[nt]);
    }
  }
  float bb[16];
#pragma unroll
  for (int nt = 0; nt < 16; ++nt) bb[nt] = b_y[nt * 16 + p];
#pragma unroll
  for (int r = 0; r < 4; ++r) {
    int row = R + q * 4 + r;
    int tI = row >> 6, bI = row & 63;
    float lg[16];
    float mx = -1e30f;
#pragma unroll
    for (int nt = 0; nt < 16; ++nt) { lg[nt] = acc[nt][r] + bb[nt]; mx = fmaxf(mx, lg[nt]); }
#pragma unroll
    for (int d = 1; d < 16; d <<= 1) mx = fmaxf(mx, __shfl_xor(mx, d));
    float s = 0.f;
#pragma unroll
    for (int nt = 0; nt < 16; ++nt) { lg[nt] = __expf(lg[nt] - mx); s += lg[nt]; }
#pragma unroll
    for (int d = 1; d < 16; d <<= 1) s += __shfl_xor(s, d);
    float inv = 1.0f / s;
    float* orow = out + ((size_t)bI * TT + tI) * NOUT;
#pragma unroll
    for (int nt = 0; nt < 16; ++nt) orow[nt * 16 + p] = lg[nt] * inv;
  }
}

extern "C" void kernel_launch(void* const* d_in, const int* in_sizes, int n_in,
                              void* d_out, int out_size, void* d_ws, size_t ws_size,
                              hipStream_t stream) {
  (void)in_sizes; (void)n_in; (void)out_size; (void)ws_size;
  const float* u   = (const float*)d_in[0];
  const float* Wuh = (const float*)d_in[1];
  const float* Whh = (const float*)d_in[2];
  const float* Why = (const float*)d_in[3];
  const float* b_h = (const float*)d_in[4];
  const float* b_y = (const float*)d_in[5];
  const float* h0  = (const float*)d_in[6];
  const float* tau = (const float*)d_in[7];
  float* out = (float*)d_out;

  char* ws = (char*)d_ws;
  unsigned short* H = (unsigned short*)ws;                       // (T+1)*64*2048 bf16
  size_t off = (size_t)(TT + 1) * BB * NH * 2;                   // 134,479,872
  unsigned short* ut = (unsigned short*)(ws + off);              // T*64*256 bf16
  off += (size_t)TT * BB * N_INP * 2;                            // +16,777,216
  unsigned short* Wyf = (unsigned short*)(ws + off);             // 2048*256 bf16 frags
  off += (size_t)NH * NOUT * 2;                                  // +1,048,576
  unsigned* flags = (unsigned*)(ws + off);                       // 513*512 dwords

  const int nz = (TT + 1) * NWAVE;
  k_zero<<<dim3((nz + 255) / 256), dim3(256), 0, stream>>>(flags, nz);
  k_ut<<<dim3(8192), dim3(256), 0, stream>>>(u, ut);
  k_swz<<<dim3((NH / 32) * (NOUT / 16)), dim3(64), 0, stream>>>(Why, Wyf, NOUT);

  void* args[] = {(void*)&Whh, (void*)&Wuh, (void*)&b_h, (void*)&tau,
                  (void*)&h0, (void*)&ut, (void*)&H, (void*)&flags};
  hipLaunchCooperativeKernel((const void*)k_step, dim3(GRIDN), dim3(1024), args, 0, stream);

  k_y<<<dim3(512), dim3(256), 0, stream>>>(H, Wyf, b_y, out);
}

// Round 8
// 7544.077 us; speedup vs baseline: 1.1190x; 1.1190x over previous
//
#include <hip/hip_runtime.h>
#include <hip/hip_fp16.h>

#define N_INP 256
#define NH    2048
#define NOUT  256
#define BB    64
#define TT    512
#define GRIDN 128          // k_step workgroups, 16 output cols each
#define NWAVE (GRIDN * 4)  // per-step flags: [row-group w][producer WG j]

typedef __bf16 bf16x8 __attribute__((ext_vector_type(8)));
typedef float  f32x4  __attribute__((ext_vector_type(4)));

__device__ __forceinline__ unsigned short f2bf(float f) {
  unsigned u = __float_as_uint(f);
  u += 0x7fffu + ((u >> 16) & 1u);          // RTNE
  return (unsigned short)(u >> 16);
}

__device__ __forceinline__ float fast_tanh(float x) {
  x = fminf(9.0f, fmaxf(-9.0f, x));
  float e = __expf(2.0f * x);
  return (e - 1.0f) / (e + 1.0f);
}

__device__ __forceinline__ f32x4 mfma16(uint4 a, uint4 b, f32x4 c) {
  return __builtin_amdgcn_mfma_f32_16x16x32_bf16(
      __builtin_bit_cast(bf16x8, a), __builtin_bit_cast(bf16x8, b), c, 0, 0, 0);
}

// ---------------- prep: zero barrier flags ----------------
__global__ void k_zero(unsigned* __restrict__ p, int n) {
  int i = blockIdx.x * 256 + threadIdx.x;
  if (i < n) p[i] = 0;
}

// ---------------- prep: u (B,T,256) f32 -> ut (T*B, 256) bf16 ----------------
__global__ void k_ut(const float* __restrict__ u, unsigned short* __restrict__ ut) {
  int idx = blockIdx.x * 256 + threadIdx.x;    // over 64*512*64 float4 units
  int k4 = idx & 63;
  int rowbt = idx >> 6;                        // row = t*64+b
  int t = rowbt >> 6, b = rowbt & 63;
  float4 f = *(const float4*)(u + ((size_t)b * TT + t) * N_INP + k4 * 4);
  uint2 pk;
  pk.x = f2bf(f.x) | ((unsigned)f2bf(f.y) << 16);
  pk.y = f2bf(f.z) | ((unsigned)f2bf(f.w) << 16);
  *(uint2*)(ut + (size_t)rowbt * N_INP + k4 * 4) = pk;
}

// ------------- prep: W (K,N) f32 row-major -> B-fragment-ordered bf16 --------
// Wf layout: [kb][nt][lane][8], blockIdx.x = kb*(N/16)+nt
__global__ void k_swz(const float* __restrict__ W, unsigned short* __restrict__ Wf, int N) {
  int lane = threadIdx.x;
  int nt16 = N >> 4;
  int kb = blockIdx.x / nt16;
  int nt = blockIdx.x - kb * nt16;
  int k0 = kb * 32 + ((lane >> 4) << 3);
  int c  = nt * 16 + (lane & 15);
  unsigned short v[8];
#pragma unroll
  for (int j = 0; j < 8; ++j) v[j] = f2bf(W[(size_t)(k0 + j) * N + c]);
  uint4 p;
  p.x = v[0] | ((unsigned)v[1] << 16);
  p.y = v[2] | ((unsigned)v[3] << 16);
  p.z = v[4] | ((unsigned)v[5] << 16);
  p.w = v[6] | ((unsigned)v[7] << 16);
  ((uint4*)Wf)[(size_t)blockIdx.x * 64 + lane] = p;
}

// ---------------- persistent recurrence kernel (cooperative) -----------------
// 128 WGs x 1024 threads (16 waves). Wave (w,h): row-group w (rows 16w..16w+16),
// K-quarter h (H-chunks 16h..16h+16, input chunks 2h..2h+1). r7 structure with
// its three measured bugs fixed:
//  (1) __launch_bounds__(1024,4) -> 128-VGPR cap: 8-deep load rotation + acc
//      fit with NO scratch (r7: VGPR=64, +204MB scratch WRITE_SIZE).
//  (2) ldsP partials in scalar [set][e][lane] layout, lane-stride 4B ->
//      conflict-free (r7: 64B/lane f32x4 stride = 32-way, 1.13e8 conflicts).
//  (3) ALL 16 waves poll producer flags directly (r4-proven one-hop poll):
//      the 4 K-quarter load chains start concurrently at detection. No
//      bar_cnt, no s_sleep relay.
// Flag/fence/store machinery byte-identical to r4-verified kernel. The 4-way
// partial-sum reassociation was proven numerically invisible by r7 (absmax
// 4.882812e-4 == baseline).
__global__ __launch_bounds__(1024, 4) void k_step(
    const float* __restrict__ Whh, const float* __restrict__ Wuh,
    const float* __restrict__ b_h, const float* __restrict__ tau,
    const float* __restrict__ h0, const unsigned short* __restrict__ ut,
    unsigned short* __restrict__ H, unsigned* __restrict__ flags) {
  __shared__ unsigned short lds[64 * 64 * 8];   // 64 KiB: W_hh frags [kb][lane][8]
  __shared__ float ldsP[12 * 16 * 64];          // 48 KiB: partials [(h-1)*4+w][e][lane]
  const int cgp = blockIdx.x;       // colgroup 0..127
  const int tid = threadIdx.x;
  const int wid = tid >> 6;         // 0..15
  const int w = wid >> 2;           // row-group 0..3
  const int h = wid & 3;            // K-quarter 0..3
  const int lane = tid & 63;
  const int q = lane >> 4, p = lane & 15;

  // one-time: stage W_hh column slice into LDS in B-fragment order
  for (int s = tid; s < 64 * 64; s += 1024) {
    int kb = s >> 6, l = s & 63;
    int k0 = kb * 32 + ((l >> 4) << 3);
    int c = cgp * 16 + (l & 15);
    unsigned short v[8];
#pragma unroll
    for (int j = 0; j < 8; ++j) v[j] = f2bf(Whh[(size_t)(k0 + j) * NH + c]);
    uint4 pk;
    pk.x = v[0] | ((unsigned)v[1] << 16);
    pk.y = v[2] | ((unsigned)v[3] << 16);
    pk.z = v[4] | ((unsigned)v[5] << 16);
    pk.w = v[6] | ((unsigned)v[7] << 16);
    ((uint4*)lds)[s] = pk;
  }

  const int c = cgp * 16 + p;                 // this lane's output column
  const float al = 1.0f / tau[c];
  const float onem = 1.0f - al;
  const float bh_c = b_h[c];
  const float h0c = fminf(1.0f, fmaxf(-1.0f, h0[c]));
  float hprev[4] = {h0c, h0c, h0c, h0c};      // used by lead wave only
  const int rbase = w * 16;                   // batch-row base of this row-group
  const bool even = (p & 1) == 0;
  const int halfc = cgp * 8 + (p >> 1);       // dword column for packed stores
  unsigned* H32 = (unsigned*)H;

  // one-time: this wave's W_uh B-fragments (input chunks 2h, 2h+1)
  uint4 wu[2];
#pragma unroll
  for (int i = 0; i < 2; ++i) {
    int kbg = 2 * h + i;
    unsigned short v[8];
#pragma unroll
    for (int j = 0; j < 8; ++j)
      v[j] = f2bf(Wuh[(size_t)(kbg * 32 + q * 8 + j) * NH + c]);
    wu[i].x = v[0] | ((unsigned)v[1] << 16);
    wu[i].y = v[2] | ((unsigned)v[3] << 16);
    wu[i].z = v[4] | ((unsigned)v[5] << 16);
    wu[i].w = v[6] | ((unsigned)v[7] << 16);
  }

  __syncthreads();   // LDS staging visible

  // init H[0]: lead waves only (cover all 16 rows of their row-group)
  if (h == 0) {
    unsigned mine = f2bf(h0c);
    unsigned other = (unsigned)__shfl_xor((int)mine, 1);
    unsigned pk0 = even ? (mine | (other << 16)) : (other | (mine << 16));
    if (even) {
#pragma unroll
      for (int r = 0; r < 4; ++r)
        __hip_atomic_store(H32 + (size_t)(rbase + q * 4 + r) * (NH / 2) + halfc,
                           pk0, __ATOMIC_RELAXED, __HIP_MEMORY_SCOPE_AGENT);
    }
    __builtin_amdgcn_fence(__ATOMIC_RELEASE, "workgroup");  // drain H[0] stores
    if (lane == 0)
      __hip_atomic_store(flags + (size_t)w * GRIDN + cgp, 1u, __ATOMIC_RELAXED,
                         __HIP_MEMORY_SCOPE_AGENT);
  }

  const uint4* ldsv = (const uint4*)lds;
  const int kb0 = h * 16;                     // this wave's H-chunk base
  float* const pslot = ldsP + (size_t)((h - 1) * 4 + w) * 16 * 64 + lane;  // h>0
  f32x4 acc[4];

  for (int t = 0; t < TT; ++t) {
    // input drive for step t (barrier-independent; overlaps flag propagation)
    {
      const uint4* Au = (const uint4*)(ut + ((size_t)t * BB + rbase + p) * N_INP + q * 8);
#pragma unroll
      for (int j = 0; j < 4; ++j) acc[j] = (f32x4){0.f, 0.f, 0.f, 0.f};
#pragma unroll
      for (int i = 0; i < 2; ++i) {
        int kbg = 2 * h + i;
        acc[kbg & 3] = mfma16(Au[kbg * 4], wu[i], acc[kbg & 3]);
      }
    }

    // one-hop wait: EVERY wave polls this row-group's 128 producers directly,
    // so all four K-quarter load chains start at the moment of detection.
    {
      const unsigned* fl = flags + (size_t)t * NWAVE + w * GRIDN;
      for (;;) {
        unsigned v0 = __hip_atomic_load(fl + lane, __ATOMIC_RELAXED,
                                        __HIP_MEMORY_SCOPE_AGENT);
        unsigned v1 = __hip_atomic_load(fl + 64 + lane, __ATOMIC_RELAXED,
                                        __HIP_MEMORY_SCOPE_AGENT);
        if (__all((v0 != 0u) && (v1 != 0u))) break;
      }
      __builtin_amdgcn_fence(__ATOMIC_ACQUIRE, "workgroup");  // compiler ordering
    }

    // this wave's 16 H-chunks (8-deep rotation, r4-proven pattern)
    const uint4* Ar = (const uint4*)(H + (size_t)t * BB * NH +
                                     (size_t)(rbase + p) * NH + q * 8);
    uint4 a[8], an[8];
#pragma unroll
    for (int j = 0; j < 8; ++j) a[j] = Ar[(kb0 + j) * 4];
#pragma unroll
    for (int j = 0; j < 8; ++j) an[j] = Ar[(kb0 + 8 + j) * 4];
#pragma unroll
    for (int j = 0; j < 8; ++j)
      acc[j & 3] = mfma16(a[j], ldsv[(kb0 + j) * 64 + lane], acc[j & 3]);
#pragma unroll
    for (int j = 0; j < 8; ++j)
      acc[j & 3] = mfma16(an[j], ldsv[(kb0 + 8 + j) * 64 + lane], acc[j & 3]);

    // combine partials across the 4 K-quarter waves (conflict-free scalar LDS)
    if (h != 0) {
#pragma unroll
      for (int ci = 0; ci < 4; ++ci)
#pragma unroll
        for (int r = 0; r < 4; ++r)
          pslot[(ci * 4 + r) * 64] = acc[ci][r];
    }
    __syncthreads();                 // partials visible to lead
    if (h == 0) {
#pragma unroll
      for (int ci = 0; ci < 4; ++ci)
#pragma unroll
        for (int r = 0; r < 4; ++r) {
          float s = acc[ci][r];
          s += ldsP[((0 * 4 + w) * 16 + ci * 4 + r) * 64 + lane];
          s += ldsP[((1 * 4 + w) * 16 + ci * 4 + r) * 64 + lane];
          s += ldsP[((2 * 4 + w) * 16 + ci * 4 + r) * 64 + lane];
          acc[ci][r] = s;
        }
    }
    __syncthreads();                 // lead has read; buffer reusable next step

    if (h == 0) {
      // epilogue: leaky update, packed write-through store of H[t+1]
      unsigned* H32n = H32 + (size_t)(t + 1) * BB * (NH / 2);
#pragma unroll
      for (int r = 0; r < 4; ++r) {
        float pre = acc[0][r] + acc[1][r] + acc[2][r] + acc[3][r] + bh_c;
        float hn = onem * hprev[r] + al * fast_tanh(pre);
        hprev[r] = hn;
        unsigned mine = f2bf(hn);
        unsigned other = (unsigned)__shfl_xor((int)mine, 1);
        unsigned pk = even ? (mine | (other << 16)) : (other | (mine << 16));
        if (even)
          __hip_atomic_store(H32n + (size_t)(rbase + q * 4 + r) * (NH / 2) + halfc,
                             pk, __ATOMIC_RELAXED, __HIP_MEMORY_SCOPE_AGENT);
      }

      __builtin_amdgcn_fence(__ATOMIC_RELEASE, "workgroup");  // drain H[t+1] stores
      if (lane == 0)
        __hip_atomic_store(flags + (size_t)(t + 1) * NWAVE + w * GRIDN + cgp, 1u,
                           __ATOMIC_RELAXED, __HIP_MEMORY_SCOPE_AGENT);
    }
  }
}

// ---------------- phase 2: Y = softmax(H[1..T] @ W_hy + b_y) -----------------
// 512 WGs x 256 thr; WG = 64 rows (wave = 16), N = 256 (16 n-tiles)
__global__ __launch_bounds__(256) void k_y(
    const unsigned short* __restrict__ H, const unsigned short* __restrict__ Wyf,
    const float* __restrict__ b_y, float* __restrict__ out) {
  int wave = threadIdx.x >> 6, lane = threadIdx.x & 63;
  int q = lane >> 4, p = lane & 15;
  int R = blockIdx.x * 64 + wave * 16;          // row = t*64+b
  const uint4* A = (const uint4*)(H + (size_t)(R + BB + p) * NH + q * 8);  // +BB: skip H[0]
  const uint4* Bf = (const uint4*)Wyf;
  f32x4 acc[16];
#pragma unroll
  for (int nt = 0; nt < 16; ++nt) acc[nt] = (f32x4){0.f, 0.f, 0.f, 0.f};
  for (int kb = 0; kb < 64; ++kb) {
    uint4 a = A[kb * 4];
#pragma unroll
    for (int nt = 0; nt < 16; ++nt) {
      uint4 b = Bf[(size_t)(kb * 16 + nt) * 64 + lane];
      acc[nt] = mfma16(a, b, acc[nt]);
    }
  }
  float bb[16];
#pragma unroll
  for (int nt = 0; nt < 16; ++nt) bb[nt] = b_y[nt * 16 + p];
#pragma unroll
  for (int r = 0; r < 4; ++r) {
    int row = R + q * 4 + r;
    int tI = row >> 6, bI = row & 63;
    float lg[16];
    float mx = -1e30f;
#pragma unroll
    for (int nt = 0; nt < 16; ++nt) { lg[nt] = acc[nt][r] + bb[nt]; mx = fmaxf(mx, lg[nt]); }
#pragma unroll
    for (int d = 1; d < 16; d <<= 1) mx = fmaxf(mx, __shfl_xor(mx, d));
    float s = 0.f;
#pragma unroll
    for (int nt = 0; nt < 16; ++nt) { lg[nt] = __expf(lg[nt] - mx); s += lg[nt]; }
#pragma unroll
    for (int d = 1; d < 16; d <<= 1) s += __shfl_xor(s, d);
    float inv = 1.0f / s;
    float* orow = out + ((size_t)bI * TT + tI) * NOUT;
#pragma unroll
    for (int nt = 0; nt < 16; ++nt) orow[nt * 16 + p] = lg[nt] * inv;
  }
}

extern "C" void kernel_launch(void* const* d_in, const int* in_sizes, int n_in,
                              void* d_out, int out_size, void* d_ws, size_t ws_size,
                              hipStream_t stream) {
  (void)in_sizes; (void)n_in; (void)out_size; (void)ws_size;
  const float* u   = (const float*)d_in[0];
  const float* Wuh = (const float*)d_in[1];
  const float* Whh = (const float*)d_in[2];
  const float* Why = (const float*)d_in[3];
  const float* b_h = (const float*)d_in[4];
  const float* b_y = (const float*)d_in[5];
  const float* h0  = (const float*)d_in[6];
  const float* tau = (const float*)d_in[7];
  float* out = (float*)d_out;

  char* ws = (char*)d_ws;
  unsigned short* H = (unsigned short*)ws;                       // (T+1)*64*2048 bf16
  size_t off = (size_t)(TT + 1) * BB * NH * 2;                   // 134,479,872
  unsigned short* ut = (unsigned short*)(ws + off);              // T*64*256 bf16
  off += (size_t)TT * BB * N_INP * 2;                            // +16,777,216
  unsigned short* Wyf = (unsigned short*)(ws + off);             // 2048*256 bf16 frags
  off += (size_t)NH * NOUT * 2;                                  // +1,048,576
  unsigned* flags = (unsigned*)(ws + off);                       // 513*512 dwords

  const int nz = (TT + 1) * NWAVE;
  k_zero<<<dim3((nz + 255) / 256), dim3(256), 0, stream>>>(flags, nz);
  k_ut<<<dim3(8192), dim3(256), 0, stream>>>(u, ut);
  k_swz<<<dim3((NH / 32) * (NOUT / 16)), dim3(64), 0, stream>>>(Why, Wyf, NOUT);

  void* args[] = {(void*)&Whh, (void*)&Wuh, (void*)&b_h, (void*)&tau,
                  (void*)&h0, (void*)&ut, (void*)&H, (void*)&flags};
  hipLaunchCooperativeKernel((const void*)k_step, dim3(GRIDN), dim3(1024), args, 0, stream);

  k_y<<<dim3(512), dim3(256), 0, stream>>>(H, Wyf, b_y, out);
}